// Round 2
// baseline (989.556 us; speedup 1.0000x reference)
//
#include <hip/hip_runtime.h>
#include <stdint.h>

typedef __attribute__((ext_vector_type(4))) float f32x4;
typedef __attribute__((ext_vector_type(8))) short s16x8;
typedef __attribute__((ext_vector_type(8))) unsigned short us8;

__device__ __forceinline__ float bf2f(unsigned short u){
  union { unsigned int i; float f; } v; v.i = ((unsigned int)u) << 16; return v.f;
}
__device__ __forceinline__ unsigned short f2bf(float f){
  union { float f; unsigned int i; } v; v.f = f;
  unsigned int r = v.i + 0x7FFFu + ((v.i >> 16) & 1u);
  return (unsigned short)(r >> 16);
}
__device__ __forceinline__ float sigm(float x){ return 1.0f / (1.0f + __expf(-x)); }

// ---------------- K0: prep ----------------
#define NA (10112*128)
#define NB 10112
#define ND 512
#define NE (256*64)

__global__ void k_prep(const float* __restrict__ Wout, const float* __restrict__ bout,
                       const float* __restrict__ bih,  const float* __restrict__ bhh,
                       const float* __restrict__ tobj, const float* __restrict__ Wtgt,
                       const float* __restrict__ btgt,
                       unsigned short* __restrict__ WoutP, float* __restrict__ boutP,
                       float* __restrict__ bsum, float* __restrict__ tgt)
{
  int tid = blockIdx.x * 256 + threadIdx.x;
  if (tid < NA){
    int vv = tid >> 7, k = tid & 127;
    float val = (vv < 10001) ? Wout[vv*128 + k] : 0.0f;
    WoutP[tid] = f2bf(val);
  } else if (tid < NA+NB){
    int vv = tid - NA;
    boutP[vv] = (vv < 10001) ? bout[vv] : -1e30f;
  } else if (tid < NA+NB+ND){
    int g = tid - NA - NB;
    bsum[g] = bih[g] + bhh[g];
  } else if (tid < NA+NB+ND+NE){
    int i = tid - NA - NB - ND; int b = i >> 6, j = i & 63;
    const float* to = tobj + b*4; const float* wt = Wtgt + j*4;
    tgt[i] = btgt[j] + to[0]*wt[0] + to[1]*wt[1] + to[2]*wt[2] + to[3]*wt[3];
  }
}

// ---------------- K1: canvas encoder (25-step LSTM, H=64) ----------------
__global__ __launch_bounds__(256) void k_canvas(
    const float* __restrict__ prevC, const float* __restrict__ finC,
    const float* __restrict__ Wobj,  const float* __restrict__ bobj,
    const float* __restrict__ ceWih, const float* __restrict__ ceWhh,
    const float* __restrict__ cebih, const float* __restrict__ cebhh,
    float* __restrict__ encP, float* __restrict__ encF)
{
  __shared__ unsigned short wih[256*64] __attribute__((aligned(16)));
  __shared__ unsigned short whh[256*64] __attribute__((aligned(16)));
  __shared__ float seq[25*4];
  __shared__ float xb[64] __attribute__((aligned(16)));
  __shared__ float hb[2][64] __attribute__((aligned(16)));
  __shared__ float gates[256];
  __shared__ float wobj_s[256];
  __shared__ float bobj_s[64];
  __shared__ float bsum_ce[256];

  int tid = threadIdx.x;
  int b = blockIdx.x & 255;
  int which = blockIdx.x >> 8;
  const float* canvas = (which ? finC : prevC) + b*100;

  // stage ce weights into LDS as bf16, XOR-swizzled 16B slots (kills stride-128B bank conflict)
  for (int i = tid; i < 2048; i += 256){
    int g = i >> 3, k8 = i & 7;
    const float* s1 = ceWih + g*64 + k8*8;
    const float* s2 = ceWhh + g*64 + k8*8;
    us8 v1, v2;
    #pragma unroll
    for (int j = 0; j < 8; j++){ v1[j] = f2bf(s1[j]); v2[j] = f2bf(s2[j]); }
    int slot = ((k8 ^ (g & 7)) * 8);
    *reinterpret_cast<us8*>(&wih[g*64 + slot]) = v1;
    *reinterpret_cast<us8*>(&whh[g*64 + slot]) = v2;
  }
  wobj_s[tid] = Wobj[tid];
  if (tid < 64) bobj_s[tid] = bobj[tid];
  bsum_ce[tid] = cebih[tid] + cebhh[tid];
  if (tid < 64) hb[0][tid] = 0.0f;
  if (tid == 0){
    int pos = 0;
    for (int i = 0; i < 25; i++){
      float a0=canvas[i*4+0], a1=canvas[i*4+1], a2=canvas[i*4+2], a3=canvas[i*4+3];
      if (a0+a1+a2+a3 >= 0.0f){
        seq[pos*4+0]=a0; seq[pos*4+1]=a1; seq[pos*4+2]=a2; seq[pos*4+3]=a3; pos++;
      }
    }
    for (; pos < 25; pos++){
      seq[pos*4+0]=-1.0f; seq[pos*4+1]=-1.0f; seq[pos*4+2]=-1.0f; seq[pos*4+3]=-1.0f;
    }
  }
  __syncthreads();

  float creg = 0.0f;
  int cur = 0;
  const float4* x4 = (const float4*)xb;

  for (int t = 0; t < 25; t++){
    if (tid < 64){
      float a = bobj_s[tid];
      a += wobj_s[tid*4+0]*seq[t*4+0] + wobj_s[tid*4+1]*seq[t*4+1]
         + wobj_s[tid*4+2]*seq[t*4+2] + wobj_s[tid*4+3]*seq[t*4+3];
      xb[tid] = a;
    }
    __syncthreads();
    float acc = bsum_ce[tid];
    const float4* h4 = (const float4*)hb[cur];
    int rowoff = tid*64;
    int sw = tid & 7;
    #pragma unroll
    for (int k8 = 0; k8 < 8; k8++){
      int slot = ((k8 ^ sw) * 8);
      us8 w1 = *reinterpret_cast<const us8*>(&wih[rowoff + slot]);
      us8 w2 = *reinterpret_cast<const us8*>(&whh[rowoff + slot]);
      float4 xa = x4[2*k8], xc = x4[2*k8+1];
      float4 ha = h4[2*k8], hc = h4[2*k8+1];
      acc += bf2f(w1[0])*xa.x + bf2f(w1[1])*xa.y + bf2f(w1[2])*xa.z + bf2f(w1[3])*xa.w;
      acc += bf2f(w1[4])*xc.x + bf2f(w1[5])*xc.y + bf2f(w1[6])*xc.z + bf2f(w1[7])*xc.w;
      acc += bf2f(w2[0])*ha.x + bf2f(w2[1])*ha.y + bf2f(w2[2])*ha.z + bf2f(w2[3])*ha.w;
      acc += bf2f(w2[4])*hc.x + bf2f(w2[5])*hc.y + bf2f(w2[6])*hc.z + bf2f(w2[7])*hc.w;
    }
    gates[tid] = acc;
    __syncthreads();
    if (tid < 64){
      float i_ = sigm(gates[tid]);
      float f_ = sigm(gates[64+tid]);
      float g_ = tanhf(gates[128+tid]);
      float o_ = sigm(gates[192+tid]);
      creg = f_*creg + i_*g_;
      hb[cur^1][tid] = o_ * tanhf(creg);
    }
    __syncthreads();
    cur ^= 1;
  }
  if (tid < 64){
    (which ? encF : encP)[b*64 + tid] = hb[cur][tid];
  }
}

// ---------------- K2: main LSTM recurrence (66 steps, H=128), Wih fused ----------------
__global__ __launch_bounds__(512, 2) void k_rec(
    const float* __restrict__ Whh, const float* __restrict__ Wih,
    const float* __restrict__ bsum, const int* __restrict__ inst,
    const float* __restrict__ embW, const float* __restrict__ tgt,
    const float* __restrict__ encP, const float* __restrict__ encF,
    unsigned short* __restrict__ Hout)
{
  int b = blockIdx.x;
  int g = threadIdx.x;
  __shared__ float xb[2][64] __attribute__((aligned(16)));
  __shared__ float hb[2][128] __attribute__((aligned(16)));
  __shared__ float gates[512];

  // each thread owns one Whh row (128 f32) + one Wih row (64 f32) in registers
  float wreg[128];
  float ureg[64];
  {
    const float4* wrow = (const float4*)(Whh + g*128);
    #pragma unroll
    for (int k4 = 0; k4 < 32; k4++){
      float4 w = wrow[k4];
      wreg[4*k4+0]=w.x; wreg[4*k4+1]=w.y; wreg[4*k4+2]=w.z; wreg[4*k4+3]=w.w;
    }
    const float4* urow = (const float4*)(Wih + g*64);
    #pragma unroll
    for (int k4 = 0; k4 < 16; k4++){
      float4 w = urow[k4];
      ureg[4*k4+0]=w.x; ureg[4*k4+1]=w.y; ureg[4*k4+2]=w.z; ureg[4*k4+3]=w.w;
    }
  }
  float bz = bsum[g];
  float creg = 0.0f;
  if (g < 128) hb[0][g] = 0.0f;
  if (g < 64)  xb[0][g] = encP[b*64+g] + encF[b*64+g];
  int cur = 0;
  __syncthreads();

  for (int s = 0; s < 66; s++){
    float a0 = bz, a1 = 0.0f, a2 = 0.0f, a3 = 0.0f;
    const float4* h4 = (const float4*)hb[cur];
    const float4* x4 = (const float4*)xb[cur];
    #pragma unroll
    for (int k4 = 0; k4 < 32; k4 += 4){
      float4 h0 = h4[k4], h1 = h4[k4+1], h2 = h4[k4+2], h3 = h4[k4+3];
      a0 += wreg[4*k4+0]*h0.x + wreg[4*k4+1]*h0.y + wreg[4*k4+2]*h0.z + wreg[4*k4+3]*h0.w;
      a1 += wreg[4*k4+4]*h1.x + wreg[4*k4+5]*h1.y + wreg[4*k4+6]*h1.z + wreg[4*k4+7]*h1.w;
      a2 += wreg[4*k4+8]*h2.x + wreg[4*k4+9]*h2.y + wreg[4*k4+10]*h2.z + wreg[4*k4+11]*h2.w;
      a3 += wreg[4*k4+12]*h3.x + wreg[4*k4+13]*h3.y + wreg[4*k4+14]*h3.z + wreg[4*k4+15]*h3.w;
    }
    #pragma unroll
    for (int k4 = 0; k4 < 16; k4 += 4){
      float4 x0 = x4[k4], x1 = x4[k4+1], x2 = x4[k4+2], x3 = x4[k4+3];
      a0 += ureg[4*k4+0]*x0.x + ureg[4*k4+1]*x0.y + ureg[4*k4+2]*x0.z + ureg[4*k4+3]*x0.w;
      a1 += ureg[4*k4+4]*x1.x + ureg[4*k4+5]*x1.y + ureg[4*k4+6]*x1.z + ureg[4*k4+7]*x1.w;
      a2 += ureg[4*k4+8]*x2.x + ureg[4*k4+9]*x2.y + ureg[4*k4+10]*x2.z + ureg[4*k4+11]*x2.w;
      a3 += ureg[4*k4+12]*x3.x + ureg[4*k4+13]*x3.y + ureg[4*k4+14]*x3.z + ureg[4*k4+15]*x3.w;
    }
    gates[g] = (a0 + a1) + (a2 + a3);
    __syncthreads();
    if (g < 128){
      float i_ = sigm(gates[g]);
      float f_ = sigm(gates[128+g]);
      float g_ = tanhf(gates[256+g]);
      float o_ = sigm(gates[384+g]);
      creg = f_*creg + i_*g_;
      float h = o_ * tanhf(creg);
      hb[cur^1][g] = h;
      if (s >= 2) Hout[((s-2)*256 + b)*128 + g] = f2bf(h);
    } else if (g < 192 && s < 65){
      // prepare x for step s+1
      int l = g - 128;
      float v;
      if (s + 1 == 1) v = tgt[b*64 + l];
      else { int tok = inst[b*65 + (s - 1)]; v = embW[tok*64 + l]; }
      xb[cur^1][l] = v;
    }
    __syncthreads();
    cur ^= 1;
  }
}

// ---------------- K3: logits GEMM + log_softmax + write (two-pass recompute) ----------------
__global__ __launch_bounds__(512) void k_out(
    const unsigned short* __restrict__ Hout, const unsigned short* __restrict__ WoutP,
    const float* __restrict__ boutP, float* __restrict__ out)
{
  int blk = blockIdx.x;
  int t = blk >> 2;
  int b0 = (blk & 3) * 64;
  int r0 = t*256 + b0;
  int tid = threadIdx.x;
  int w = tid >> 6;
  int l = tid & 63;
  int rowg = (w & 3) * 16;
  int ch = w >> 2;

  __shared__ float rs_l[2][64];
  __shared__ float lse_l[64];

  // A fragments for this wave's 16 rows, full K=128, held in registers
  s16x8 afrag[4];
  {
    int arow = r0 + rowg + (l & 15);
    const s16x8* ap = (const s16x8*)(Hout + arow*128 + ((l >> 4) * 8));
    #pragma unroll
    for (int kk = 0; kk < 4; kk++) afrag[kk] = ap[kk*4];
  }

  // pass 1: row sums of exp(logit)
  float rs[4] = {0,0,0,0};
  #pragma unroll 2
  for (int tile = ch; tile < 632; tile += 2){
    f32x4 acc = {0,0,0,0};
    const s16x8* bp = (const s16x8*)(WoutP + (tile*16 + (l & 15))*128 + ((l >> 4) * 8));
    #pragma unroll
    for (int kk = 0; kk < 4; kk++){
      s16x8 bfrag = bp[kk*4];
      acc = __builtin_amdgcn_mfma_f32_16x16x32_bf16(afrag[kk], bfrag, acc, 0, 0, 0);
    }
    int v = tile*16 + (l & 15);
    float bo = boutP[v];
    #pragma unroll
    for (int i = 0; i < 4; i++) rs[i] += __expf(acc[i] + bo);
  }
  #pragma unroll
  for (int i = 0; i < 4; i++){
    float s = rs[i];
    s += __shfl_xor(s, 1); s += __shfl_xor(s, 2);
    s += __shfl_xor(s, 4); s += __shfl_xor(s, 8);
    rs[i] = s;
  }
  if ((l & 15) == 0){
    #pragma unroll
    for (int i = 0; i < 4; i++) rs_l[ch][rowg + (l >> 4)*4 + i] = rs[i];
  }
  __syncthreads();
  if (tid < 64) lse_l[tid] = logf(rs_l[0][tid] + rs_l[1][tid]);
  __syncthreads();

  float mylse[4];
  #pragma unroll
  for (int i = 0; i < 4; i++) mylse[i] = lse_l[rowg + (l >> 4)*4 + i];

  // pass 2: recompute logits, write logit - lse
  #pragma unroll 2
  for (int tile = ch; tile < 632; tile += 2){
    f32x4 acc = {0,0,0,0};
    const s16x8* bp = (const s16x8*)(WoutP + (tile*16 + (l & 15))*128 + ((l >> 4) * 8));
    #pragma unroll
    for (int kk = 0; kk < 4; kk++){
      s16x8 bfrag = bp[kk*4];
      acc = __builtin_amdgcn_mfma_f32_16x16x32_bf16(afrag[kk], bfrag, acc, 0, 0, 0);
    }
    int v = tile*16 + (l & 15);
    if (v < 10001){
      float bo = boutP[v];
      #pragma unroll
      for (int i = 0; i < 4; i++){
        int rib = rowg + (l >> 4)*4 + i;
        size_t oidx = (size_t)((b0 + rib)*64 + t) * 10001u + (unsigned)v;
        out[oidx] = acc[i] + bo - mylse[i];
      }
    }
  }
}

// ---------------- host launcher ----------------
extern "C" void kernel_launch(void* const* d_in, const int* in_sizes, int n_in,
                              void* d_out, int out_size, void* d_ws, size_t ws_size,
                              hipStream_t stream)
{
  (void)in_sizes; (void)n_in; (void)out_size; (void)ws_size;
  const int*   inst    = (const int*)  d_in[0];
  const float* prevC   = (const float*)d_in[1];
  const float* finC    = (const float*)d_in[2];
  const float* tobj    = (const float*)d_in[3];
  const float* embW    = (const float*)d_in[4];
  const float* Wih     = (const float*)d_in[5];
  const float* Whh     = (const float*)d_in[6];
  const float* bih     = (const float*)d_in[7];
  const float* bhh     = (const float*)d_in[8];
  const float* Wout    = (const float*)d_in[9];
  const float* bout    = (const float*)d_in[10];
  const float* Wtgt    = (const float*)d_in[11];
  const float* btgt    = (const float*)d_in[12];
  const float* Wobj    = (const float*)d_in[13];
  const float* bobj    = (const float*)d_in[14];
  const float* ceWih   = (const float*)d_in[15];
  const float* ceWhh   = (const float*)d_in[16];
  const float* cebih   = (const float*)d_in[17];
  const float* cebhh   = (const float*)d_in[18];

  char* ws = (char*)d_ws;
  unsigned short* WoutP = (unsigned short*)(ws + 0);         // 10112*128*2 = 2,588,672
  float* boutP = (float*)(ws + 2588672);                     // 10112*4     = 40,448
  float* bsum  = (float*)(ws + 2629120);                     // 512*4       = 2,048
  float* tgt   = (float*)(ws + 2631168);                     // 256*64*4    = 65,536
  float* encP  = (float*)(ws + 2696704);                     // 256*64*4    = 65,536
  float* encF  = (float*)(ws + 2762240);                     // 256*64*4    = 65,536
  unsigned short* Hout = (unsigned short*)(ws + 2827776);    // 64*256*128*2 = 4,194,304
  // total ws use: 7,022,080 bytes (~7 MB)
  float* out = (float*)d_out;

  k_prep  <<<5162, 256, 0, stream>>>(Wout, bout, bih, bhh, tobj, Wtgt, btgt,
                                     WoutP, boutP, bsum, tgt);
  k_canvas<<<512, 256, 0, stream>>>(prevC, finC, Wobj, bobj, ceWih, ceWhh,
                                    cebih, cebhh, encP, encF);
  k_rec   <<<256, 512, 0, stream>>>(Whh, Wih, bsum, inst, embW, tgt, encP, encF, Hout);
  k_out   <<<256, 512, 0, stream>>>(Hout, WoutP, boutP, out);
}

// Round 3
// 882.080 us; speedup vs baseline: 1.1218x; 1.1218x over previous
//
#include <hip/hip_runtime.h>
#include <stdint.h>

typedef __attribute__((ext_vector_type(4))) float f32x4;
typedef __attribute__((ext_vector_type(8))) short s16x8;
typedef __attribute__((ext_vector_type(8))) unsigned short us8;

__device__ __forceinline__ float bf2f(unsigned short u){
  union { unsigned int i; float f; } v; v.i = ((unsigned int)u) << 16; return v.f;
}
__device__ __forceinline__ unsigned short f2bf(float f){
  union { float f; unsigned int i; } v; v.f = f;
  unsigned int r = v.i + 0x7FFFu + ((v.i >> 16) & 1u);
  return (unsigned short)(r >> 16);
}
__device__ __forceinline__ float sigm(float x){ return 1.0f / (1.0f + __expf(-x)); }

// ---------------- K0: prep ----------------
#define NA (10112*128)
#define NB 10112
#define ND 512
#define NE (256*64)

__global__ void k_prep(const float* __restrict__ Wout, const float* __restrict__ bout,
                       const float* __restrict__ bih,  const float* __restrict__ bhh,
                       const float* __restrict__ tobj, const float* __restrict__ Wtgt,
                       const float* __restrict__ btgt,
                       unsigned short* __restrict__ WoutP, float* __restrict__ boutP,
                       float* __restrict__ bsum, float* __restrict__ tgt)
{
  int tid = blockIdx.x * 256 + threadIdx.x;
  if (tid < NA){
    int vv = tid >> 7, k = tid & 127;
    float val = (vv < 10001) ? Wout[vv*128 + k] : 0.0f;
    WoutP[tid] = f2bf(val);
  } else if (tid < NA+NB){
    int vv = tid - NA;
    boutP[vv] = (vv < 10001) ? bout[vv] : -1e30f;
  } else if (tid < NA+NB+ND){
    int g = tid - NA - NB;
    bsum[g] = bih[g] + bhh[g];
  } else if (tid < NA+NB+ND+NE){
    int i = tid - NA - NB - ND; int b = i >> 6, j = i & 63;
    const float* to = tobj + b*4; const float* wt = Wtgt + j*4;
    tgt[i] = btgt[j] + to[0]*wt[0] + to[1]*wt[1] + to[2]*wt[2] + to[3]*wt[3];
  }
}

// ---------------- K1: canvas encoder (25-step LSTM, H=64) ----------------
__global__ __launch_bounds__(256) void k_canvas(
    const float* __restrict__ prevC, const float* __restrict__ finC,
    const float* __restrict__ Wobj,  const float* __restrict__ bobj,
    const float* __restrict__ ceWih, const float* __restrict__ ceWhh,
    const float* __restrict__ cebih, const float* __restrict__ cebhh,
    float* __restrict__ encP, float* __restrict__ encF)
{
  __shared__ unsigned short wih[256*64] __attribute__((aligned(16)));
  __shared__ unsigned short whh[256*64] __attribute__((aligned(16)));
  __shared__ float seq[25*4];
  __shared__ float xb[64] __attribute__((aligned(16)));
  __shared__ float hb[2][64] __attribute__((aligned(16)));
  __shared__ float gates[256];
  __shared__ float wobj_s[256];
  __shared__ float bobj_s[64];
  __shared__ float bsum_ce[256];

  int tid = threadIdx.x;
  int b = blockIdx.x & 255;
  int which = blockIdx.x >> 8;
  const float* canvas = (which ? finC : prevC) + b*100;

  for (int i = tid; i < 2048; i += 256){
    int g = i >> 3, k8 = i & 7;
    const float* s1 = ceWih + g*64 + k8*8;
    const float* s2 = ceWhh + g*64 + k8*8;
    us8 v1, v2;
    #pragma unroll
    for (int j = 0; j < 8; j++){ v1[j] = f2bf(s1[j]); v2[j] = f2bf(s2[j]); }
    int slot = ((k8 ^ (g & 7)) * 8);
    *reinterpret_cast<us8*>(&wih[g*64 + slot]) = v1;
    *reinterpret_cast<us8*>(&whh[g*64 + slot]) = v2;
  }
  wobj_s[tid] = Wobj[tid];
  if (tid < 64) bobj_s[tid] = bobj[tid];
  bsum_ce[tid] = cebih[tid] + cebhh[tid];
  if (tid < 64) hb[0][tid] = 0.0f;
  if (tid == 0){
    int pos = 0;
    for (int i = 0; i < 25; i++){
      float a0=canvas[i*4+0], a1=canvas[i*4+1], a2=canvas[i*4+2], a3=canvas[i*4+3];
      if (a0+a1+a2+a3 >= 0.0f){
        seq[pos*4+0]=a0; seq[pos*4+1]=a1; seq[pos*4+2]=a2; seq[pos*4+3]=a3; pos++;
      }
    }
    for (; pos < 25; pos++){
      seq[pos*4+0]=-1.0f; seq[pos*4+1]=-1.0f; seq[pos*4+2]=-1.0f; seq[pos*4+3]=-1.0f;
    }
  }
  __syncthreads();

  float creg = 0.0f;
  int cur = 0;
  const float4* x4 = (const float4*)xb;

  for (int t = 0; t < 25; t++){
    if (tid < 64){
      float a = bobj_s[tid];
      a += wobj_s[tid*4+0]*seq[t*4+0] + wobj_s[tid*4+1]*seq[t*4+1]
         + wobj_s[tid*4+2]*seq[t*4+2] + wobj_s[tid*4+3]*seq[t*4+3];
      xb[tid] = a;
    }
    __syncthreads();
    float acc = bsum_ce[tid];
    const float4* h4 = (const float4*)hb[cur];
    int rowoff = tid*64;
    int sw = tid & 7;
    #pragma unroll
    for (int k8 = 0; k8 < 8; k8++){
      int slot = ((k8 ^ sw) * 8);
      us8 w1 = *reinterpret_cast<const us8*>(&wih[rowoff + slot]);
      us8 w2 = *reinterpret_cast<const us8*>(&whh[rowoff + slot]);
      float4 xa = x4[2*k8], xc = x4[2*k8+1];
      float4 ha = h4[2*k8], hc = h4[2*k8+1];
      acc += bf2f(w1[0])*xa.x + bf2f(w1[1])*xa.y + bf2f(w1[2])*xa.z + bf2f(w1[3])*xa.w;
      acc += bf2f(w1[4])*xc.x + bf2f(w1[5])*xc.y + bf2f(w1[6])*xc.z + bf2f(w1[7])*xc.w;
      acc += bf2f(w2[0])*ha.x + bf2f(w2[1])*ha.y + bf2f(w2[2])*ha.z + bf2f(w2[3])*ha.w;
      acc += bf2f(w2[4])*hc.x + bf2f(w2[5])*hc.y + bf2f(w2[6])*hc.z + bf2f(w2[7])*hc.w;
    }
    gates[tid] = acc;
    __syncthreads();
    if (tid < 64){
      float i_ = sigm(gates[tid]);
      float f_ = sigm(gates[64+tid]);
      float g_ = tanhf(gates[128+tid]);
      float o_ = sigm(gates[192+tid]);
      creg = f_*creg + i_*g_;
      hb[cur^1][tid] = o_ * tanhf(creg);
    }
    __syncthreads();
    cur ^= 1;
  }
  if (tid < 64){
    (which ? encF : encP)[b*64 + tid] = hb[cur][tid];
  }
}

// ---------------- K2: main LSTM recurrence (66 steps, H=128), Wih fused ----------------
__global__ __launch_bounds__(512, 2) void k_rec(
    const float* __restrict__ Whh, const float* __restrict__ Wih,
    const float* __restrict__ bsum, const int* __restrict__ inst,
    const float* __restrict__ embW, const float* __restrict__ tgt,
    const float* __restrict__ encP, const float* __restrict__ encF,
    unsigned short* __restrict__ Hout)
{
  int b = blockIdx.x;
  int g = threadIdx.x;
  __shared__ float xb[2][64] __attribute__((aligned(16)));
  __shared__ float hb[2][128] __attribute__((aligned(16)));
  __shared__ float gates[512];

  float wreg[128];
  float ureg[64];
  {
    const float4* wrow = (const float4*)(Whh + g*128);
    #pragma unroll
    for (int k4 = 0; k4 < 32; k4++){
      float4 w = wrow[k4];
      wreg[4*k4+0]=w.x; wreg[4*k4+1]=w.y; wreg[4*k4+2]=w.z; wreg[4*k4+3]=w.w;
    }
    const float4* urow = (const float4*)(Wih + g*64);
    #pragma unroll
    for (int k4 = 0; k4 < 16; k4++){
      float4 w = urow[k4];
      ureg[4*k4+0]=w.x; ureg[4*k4+1]=w.y; ureg[4*k4+2]=w.z; ureg[4*k4+3]=w.w;
    }
  }
  float bz = bsum[g];
  float creg = 0.0f;
  if (g < 128) hb[0][g] = 0.0f;
  if (g < 64)  xb[0][g] = encP[b*64+g] + encF[b*64+g];
  int cur = 0;
  __syncthreads();

  for (int s = 0; s < 66; s++){
    float a0 = bz, a1 = 0.0f, a2 = 0.0f, a3 = 0.0f;
    const float4* h4 = (const float4*)hb[cur];
    const float4* x4 = (const float4*)xb[cur];
    #pragma unroll
    for (int k4 = 0; k4 < 32; k4 += 4){
      float4 h0 = h4[k4], h1 = h4[k4+1], h2 = h4[k4+2], h3 = h4[k4+3];
      a0 += wreg[4*k4+0]*h0.x + wreg[4*k4+1]*h0.y + wreg[4*k4+2]*h0.z + wreg[4*k4+3]*h0.w;
      a1 += wreg[4*k4+4]*h1.x + wreg[4*k4+5]*h1.y + wreg[4*k4+6]*h1.z + wreg[4*k4+7]*h1.w;
      a2 += wreg[4*k4+8]*h2.x + wreg[4*k4+9]*h2.y + wreg[4*k4+10]*h2.z + wreg[4*k4+11]*h2.w;
      a3 += wreg[4*k4+12]*h3.x + wreg[4*k4+13]*h3.y + wreg[4*k4+14]*h3.z + wreg[4*k4+15]*h3.w;
    }
    #pragma unroll
    for (int k4 = 0; k4 < 16; k4 += 4){
      float4 x0 = x4[k4], x1 = x4[k4+1], x2 = x4[k4+2], x3 = x4[k4+3];
      a0 += ureg[4*k4+0]*x0.x + ureg[4*k4+1]*x0.y + ureg[4*k4+2]*x0.z + ureg[4*k4+3]*x0.w;
      a1 += ureg[4*k4+4]*x1.x + ureg[4*k4+5]*x1.y + ureg[4*k4+6]*x1.z + ureg[4*k4+7]*x1.w;
      a2 += ureg[4*k4+8]*x2.x + ureg[4*k4+9]*x2.y + ureg[4*k4+10]*x2.z + ureg[4*k4+11]*x2.w;
      a3 += ureg[4*k4+12]*x3.x + ureg[4*k4+13]*x3.y + ureg[4*k4+14]*x3.z + ureg[4*k4+15]*x3.w;
    }
    gates[g] = (a0 + a1) + (a2 + a3);
    __syncthreads();
    if (g < 128){
      float i_ = sigm(gates[g]);
      float f_ = sigm(gates[128+g]);
      float g_ = tanhf(gates[256+g]);
      float o_ = sigm(gates[384+g]);
      creg = f_*creg + i_*g_;
      float h = o_ * tanhf(creg);
      hb[cur^1][g] = h;
      if (s >= 2) Hout[((s-2)*256 + b)*128 + g] = f2bf(h);
    } else if (g < 192 && s < 65){
      int l = g - 128;
      float v;
      if (s + 1 == 1) v = tgt[b*64 + l];
      else { int tok = inst[b*65 + (s - 1)]; v = embW[tok*64 + l]; }
      xb[cur^1][l] = v;
    }
    __syncthreads();
    cur ^= 1;
  }
}

// ---------------- K3: logits GEMM + log_softmax, LDS-staged coalesced writes ----------
// grid: 512 blocks = 64 t * 8 row-octets of 32 b-rows; 8 waves: rg = w&1, ch = w>>1
__global__ __launch_bounds__(512, 4) void k_out(
    const unsigned short* __restrict__ Hout, const unsigned short* __restrict__ WoutP,
    const float* __restrict__ boutP, float* __restrict__ out)
{
  int blk = blockIdx.x;
  int t = blk >> 3;
  int b0 = (blk & 7) * 32;
  int r0 = t*256 + b0;
  int tid = threadIdx.x;
  int w = tid >> 6;
  int l = tid & 63;
  int rg = w & 1;
  int ch = w >> 1;        // 0..3
  int rowg = rg * 16;

  __shared__ float rs_l[4][32];
  __shared__ float lse_l[32];
  __shared__ float stage[2][32][132] __attribute__((aligned(16)));

  // A fragments: 16 rows, full K=128, in registers
  s16x8 afrag[4];
  {
    int arow = r0 + rowg + (l & 15);
    const s16x8* ap = (const s16x8*)(Hout + arow*128 + ((l >> 4) * 8));
    #pragma unroll
    for (int kk = 0; kk < 4; kk++) afrag[kk] = ap[kk*4];
  }

  // ---- pass 1: row sums of exp(logit) ----
  float rs[4] = {0,0,0,0};
  #pragma unroll 2
  for (int tile = ch; tile < 632; tile += 4){
    f32x4 acc = {0,0,0,0};
    const s16x8* bp = (const s16x8*)(WoutP + (tile*16 + (l & 15))*128 + ((l >> 4) * 8));
    #pragma unroll
    for (int kk = 0; kk < 4; kk++){
      s16x8 bfrag = bp[kk*4];
      acc = __builtin_amdgcn_mfma_f32_16x16x32_bf16(afrag[kk], bfrag, acc, 0, 0, 0);
    }
    float bo = boutP[tile*16 + (l & 15)];
    #pragma unroll
    for (int i = 0; i < 4; i++) rs[i] += __expf(acc[i] + bo);
  }
  #pragma unroll
  for (int i = 0; i < 4; i++){
    float s = rs[i];
    s += __shfl_xor(s, 1); s += __shfl_xor(s, 2);
    s += __shfl_xor(s, 4); s += __shfl_xor(s, 8);
    rs[i] = s;
  }
  if ((l & 15) == 0){
    #pragma unroll
    for (int i = 0; i < 4; i++) rs_l[ch][rowg + (l >> 4)*4 + i] = rs[i];
  }
  __syncthreads();
  if (tid < 32) lse_l[tid] = logf(rs_l[0][tid] + rs_l[1][tid] + rs_l[2][tid] + rs_l[3][tid]);
  __syncthreads();

  float mylse[4];
  #pragma unroll
  for (int i = 0; i < 4; i++) mylse[i] = lse_l[rowg + (l >> 4)*4 + i];

  // ---- pass 2: recompute logits per 128-col chunk, stage in LDS, coalesced write ----
  int wrow0[8], wcol0[8];
  #pragma unroll
  for (int j = 0; j < 8; j++){
    int e = j*512 + tid;
    wrow0[j] = e >> 7;
    wcol0[j] = e & 127;
  }

  for (int chunk = 0; chunk < 79; chunk++){
    float (*sb)[132] = stage[chunk & 1];
    #pragma unroll
    for (int p = 0; p < 2; p++){
      int tile = chunk*8 + ch*2 + p;
      f32x4 acc = {0,0,0,0};
      const s16x8* bp = (const s16x8*)(WoutP + (tile*16 + (l & 15))*128 + ((l >> 4) * 8));
      #pragma unroll
      for (int kk = 0; kk < 4; kk++){
        s16x8 bfrag = bp[kk*4];
        acc = __builtin_amdgcn_mfma_f32_16x16x32_bf16(afrag[kk], bfrag, acc, 0, 0, 0);
      }
      float bo = boutP[tile*16 + (l & 15)];
      int colb = (ch*2 + p)*16 + (l & 15);
      #pragma unroll
      for (int i = 0; i < 4; i++){
        sb[rowg + (l >> 4)*4 + i][colb] = acc[i] + bo - mylse[i];
      }
    }
    __syncthreads();
    // write phase: each wave stores 64 consecutive dwords (256 B contiguous)
    int vbase = chunk * 128;
    if (chunk < 78){
      #pragma unroll
      for (int j = 0; j < 8; j++){
        int row = wrow0[j], col = wcol0[j];
        size_t oidx = (size_t)((b0 + row)*64 + t) * 10001u + (unsigned)(vbase + col);
        out[oidx] = sb[row][col];
      }
    } else {
      #pragma unroll
      for (int j = 0; j < 8; j++){
        int row = wrow0[j], col = wcol0[j];
        int v = vbase + col;
        if (v < 10001){
          size_t oidx = (size_t)((b0 + row)*64 + t) * 10001u + (unsigned)v;
          out[oidx] = sb[row][col];
        }
      }
    }
    // double-buffered stage: single barrier per chunk is safe
    __syncthreads();
  }
}

// ---------------- host launcher ----------------
extern "C" void kernel_launch(void* const* d_in, const int* in_sizes, int n_in,
                              void* d_out, int out_size, void* d_ws, size_t ws_size,
                              hipStream_t stream)
{
  (void)in_sizes; (void)n_in; (void)out_size; (void)ws_size;
  const int*   inst    = (const int*)  d_in[0];
  const float* prevC   = (const float*)d_in[1];
  const float* finC    = (const float*)d_in[2];
  const float* tobj    = (const float*)d_in[3];
  const float* embW    = (const float*)d_in[4];
  const float* Wih     = (const float*)d_in[5];
  const float* Whh     = (const float*)d_in[6];
  const float* bih     = (const float*)d_in[7];
  const float* bhh     = (const float*)d_in[8];
  const float* Wout    = (const float*)d_in[9];
  const float* bout    = (const float*)d_in[10];
  const float* Wtgt    = (const float*)d_in[11];
  const float* btgt    = (const float*)d_in[12];
  const float* Wobj    = (const float*)d_in[13];
  const float* bobj    = (const float*)d_in[14];
  const float* ceWih   = (const float*)d_in[15];
  const float* ceWhh   = (const float*)d_in[16];
  const float* cebih   = (const float*)d_in[17];
  const float* cebhh   = (const float*)d_in[18];

  char* ws = (char*)d_ws;
  unsigned short* WoutP = (unsigned short*)(ws + 0);         // 10112*128*2 = 2,588,672
  float* boutP = (float*)(ws + 2588672);                     // 10112*4     = 40,448
  float* bsum  = (float*)(ws + 2629120);                     // 512*4       = 2,048
  float* tgt   = (float*)(ws + 2631168);                     // 256*64*4    = 65,536
  float* encP  = (float*)(ws + 2696704);                     // 256*64*4    = 65,536
  float* encF  = (float*)(ws + 2762240);                     // 256*64*4    = 65,536
  unsigned short* Hout = (unsigned short*)(ws + 2827776);    // 64*256*128*2 = 4,194,304
  float* out = (float*)d_out;

  k_prep  <<<5162, 256, 0, stream>>>(Wout, bout, bih, bhh, tobj, Wtgt, btgt,
                                     WoutP, boutP, bsum, tgt);
  k_canvas<<<512, 256, 0, stream>>>(prevC, finC, Wobj, bobj, ceWih, ceWhh,
                                    cebih, cebhh, encP, encF);
  k_rec   <<<256, 512, 0, stream>>>(Whh, Wih, bsum, inst, embW, tgt, encP, encF, Hout);
  k_out   <<<512, 512, 0, stream>>>(Hout, WoutP, boutP, out);
}

// Round 4
// 592.747 us; speedup vs baseline: 1.6694x; 1.4881x over previous
//
#include <hip/hip_runtime.h>
#include <stdint.h>

typedef __attribute__((ext_vector_type(4))) float f32x4;
typedef __attribute__((ext_vector_type(8))) short s16x8;
typedef __attribute__((ext_vector_type(8))) unsigned short us8;

__device__ __forceinline__ float bf2f(unsigned short u){
  union { unsigned int i; float f; } v; v.i = ((unsigned int)u) << 16; return v.f;
}
__device__ __forceinline__ unsigned short f2bf(float f){
  union { float f; unsigned int i; } v; v.f = f;
  unsigned int r = v.i + 0x7FFFu + ((v.i >> 16) & 1u);
  return (unsigned short)(r >> 16);
}
__device__ __forceinline__ float sigm(float x){ return 1.0f / (1.0f + __expf(-x)); }

// ---------------- K0: prep ----------------
#define NA (10112*128)
#define NB 10112
#define ND 512
#define NE (256*64)

__global__ void k_prep(const float* __restrict__ Wout, const float* __restrict__ bout,
                       const float* __restrict__ bih,  const float* __restrict__ bhh,
                       const float* __restrict__ tobj, const float* __restrict__ Wtgt,
                       const float* __restrict__ btgt,
                       unsigned short* __restrict__ WoutP, float* __restrict__ boutP,
                       float* __restrict__ bsum, float* __restrict__ tgt)
{
  int tid = blockIdx.x * 256 + threadIdx.x;
  if (tid < NA){
    int vv = tid >> 7, k = tid & 127;
    float val = (vv < 10001) ? Wout[vv*128 + k] : 0.0f;
    WoutP[tid] = f2bf(val);
  } else if (tid < NA+NB){
    int vv = tid - NA;
    boutP[vv] = (vv < 10001) ? bout[vv] : -1e30f;
  } else if (tid < NA+NB+ND){
    int g = tid - NA - NB;
    bsum[g] = bih[g] + bhh[g];
  } else if (tid < NA+NB+ND+NE){
    int i = tid - NA - NB - ND; int b = i >> 6, j = i & 63;
    const float* to = tobj + b*4; const float* wt = Wtgt + j*4;
    tgt[i] = btgt[j] + to[0]*wt[0] + to[1]*wt[1] + to[2]*wt[2] + to[3]*wt[3];
  }
}

// ---------------- K1: canvas encoder (25-step LSTM, H=64) ----------------
__global__ __launch_bounds__(256) void k_canvas(
    const float* __restrict__ prevC, const float* __restrict__ finC,
    const float* __restrict__ Wobj,  const float* __restrict__ bobj,
    const float* __restrict__ ceWih, const float* __restrict__ ceWhh,
    const float* __restrict__ cebih, const float* __restrict__ cebhh,
    float* __restrict__ encP, float* __restrict__ encF)
{
  __shared__ unsigned short wih[256*64] __attribute__((aligned(16)));
  __shared__ unsigned short whh[256*64] __attribute__((aligned(16)));
  __shared__ float seq[25*4];
  __shared__ float xb[64] __attribute__((aligned(16)));
  __shared__ float hb[2][64] __attribute__((aligned(16)));
  __shared__ float gates[256];
  __shared__ float wobj_s[256];
  __shared__ float bobj_s[64];
  __shared__ float bsum_ce[256];

  int tid = threadIdx.x;
  int b = blockIdx.x & 255;
  int which = blockIdx.x >> 8;
  const float* canvas = (which ? finC : prevC) + b*100;

  for (int i = tid; i < 2048; i += 256){
    int g = i >> 3, k8 = i & 7;
    const float* s1 = ceWih + g*64 + k8*8;
    const float* s2 = ceWhh + g*64 + k8*8;
    us8 v1, v2;
    #pragma unroll
    for (int j = 0; j < 8; j++){ v1[j] = f2bf(s1[j]); v2[j] = f2bf(s2[j]); }
    int slot = ((k8 ^ (g & 7)) * 8);
    *reinterpret_cast<us8*>(&wih[g*64 + slot]) = v1;
    *reinterpret_cast<us8*>(&whh[g*64 + slot]) = v2;
  }
  wobj_s[tid] = Wobj[tid];
  if (tid < 64) bobj_s[tid] = bobj[tid];
  bsum_ce[tid] = cebih[tid] + cebhh[tid];
  if (tid < 64) hb[0][tid] = 0.0f;
  if (tid == 0){
    int pos = 0;
    for (int i = 0; i < 25; i++){
      float a0=canvas[i*4+0], a1=canvas[i*4+1], a2=canvas[i*4+2], a3=canvas[i*4+3];
      if (a0+a1+a2+a3 >= 0.0f){
        seq[pos*4+0]=a0; seq[pos*4+1]=a1; seq[pos*4+2]=a2; seq[pos*4+3]=a3; pos++;
      }
    }
    for (; pos < 25; pos++){
      seq[pos*4+0]=-1.0f; seq[pos*4+1]=-1.0f; seq[pos*4+2]=-1.0f; seq[pos*4+3]=-1.0f;
    }
  }
  __syncthreads();

  float creg = 0.0f;
  int cur = 0;
  const float4* x4 = (const float4*)xb;

  for (int t = 0; t < 25; t++){
    if (tid < 64){
      float a = bobj_s[tid];
      a += wobj_s[tid*4+0]*seq[t*4+0] + wobj_s[tid*4+1]*seq[t*4+1]
         + wobj_s[tid*4+2]*seq[t*4+2] + wobj_s[tid*4+3]*seq[t*4+3];
      xb[tid] = a;
    }
    __syncthreads();
    float acc = bsum_ce[tid];
    const float4* h4 = (const float4*)hb[cur];
    int rowoff = tid*64;
    int sw = tid & 7;
    #pragma unroll
    for (int k8 = 0; k8 < 8; k8++){
      int slot = ((k8 ^ sw) * 8);
      us8 w1 = *reinterpret_cast<const us8*>(&wih[rowoff + slot]);
      us8 w2 = *reinterpret_cast<const us8*>(&whh[rowoff + slot]);
      float4 xa = x4[2*k8], xc = x4[2*k8+1];
      float4 ha = h4[2*k8], hc = h4[2*k8+1];
      acc += bf2f(w1[0])*xa.x + bf2f(w1[1])*xa.y + bf2f(w1[2])*xa.z + bf2f(w1[3])*xa.w;
      acc += bf2f(w1[4])*xc.x + bf2f(w1[5])*xc.y + bf2f(w1[6])*xc.z + bf2f(w1[7])*xc.w;
      acc += bf2f(w2[0])*ha.x + bf2f(w2[1])*ha.y + bf2f(w2[2])*ha.z + bf2f(w2[3])*ha.w;
      acc += bf2f(w2[4])*hc.x + bf2f(w2[5])*hc.y + bf2f(w2[6])*hc.z + bf2f(w2[7])*hc.w;
    }
    gates[tid] = acc;
    __syncthreads();
    if (tid < 64){
      float i_ = sigm(gates[tid]);
      float f_ = sigm(gates[64+tid]);
      float g_ = tanhf(gates[128+tid]);
      float o_ = sigm(gates[192+tid]);
      creg = f_*creg + i_*g_;
      hb[cur^1][tid] = o_ * tanhf(creg);
    }
    __syncthreads();
    cur ^= 1;
  }
  if (tid < 64){
    (which ? encF : encP)[b*64 + tid] = hb[cur][tid];
  }
}

// ---------------- K2: main LSTM recurrence (66 steps, H=128), Wih fused ----------------
__global__ __launch_bounds__(512, 2) void k_rec(
    const float* __restrict__ Whh, const float* __restrict__ Wih,
    const float* __restrict__ bsum, const int* __restrict__ inst,
    const float* __restrict__ embW, const float* __restrict__ tgt,
    const float* __restrict__ encP, const float* __restrict__ encF,
    unsigned short* __restrict__ Hout)
{
  int b = blockIdx.x;
  int g = threadIdx.x;
  __shared__ float xb[2][64] __attribute__((aligned(16)));
  __shared__ float hb[2][128] __attribute__((aligned(16)));
  __shared__ float gates[512];

  float wreg[128];
  float ureg[64];
  {
    const float4* wrow = (const float4*)(Whh + g*128);
    #pragma unroll
    for (int k4 = 0; k4 < 32; k4++){
      float4 w = wrow[k4];
      wreg[4*k4+0]=w.x; wreg[4*k4+1]=w.y; wreg[4*k4+2]=w.z; wreg[4*k4+3]=w.w;
    }
    const float4* urow = (const float4*)(Wih + g*64);
    #pragma unroll
    for (int k4 = 0; k4 < 16; k4++){
      float4 w = urow[k4];
      ureg[4*k4+0]=w.x; ureg[4*k4+1]=w.y; ureg[4*k4+2]=w.z; ureg[4*k4+3]=w.w;
    }
  }
  float bz = bsum[g];
  float creg = 0.0f;
  if (g < 128) hb[0][g] = 0.0f;
  if (g < 64)  xb[0][g] = encP[b*64+g] + encF[b*64+g];
  int cur = 0;
  __syncthreads();

  for (int s = 0; s < 66; s++){
    float a0 = bz, a1 = 0.0f, a2 = 0.0f, a3 = 0.0f;
    const float4* h4 = (const float4*)hb[cur];
    const float4* x4 = (const float4*)xb[cur];
    #pragma unroll
    for (int k4 = 0; k4 < 32; k4 += 4){
      float4 h0 = h4[k4], h1 = h4[k4+1], h2 = h4[k4+2], h3 = h4[k4+3];
      a0 += wreg[4*k4+0]*h0.x + wreg[4*k4+1]*h0.y + wreg[4*k4+2]*h0.z + wreg[4*k4+3]*h0.w;
      a1 += wreg[4*k4+4]*h1.x + wreg[4*k4+5]*h1.y + wreg[4*k4+6]*h1.z + wreg[4*k4+7]*h1.w;
      a2 += wreg[4*k4+8]*h2.x + wreg[4*k4+9]*h2.y + wreg[4*k4+10]*h2.z + wreg[4*k4+11]*h2.w;
      a3 += wreg[4*k4+12]*h3.x + wreg[4*k4+13]*h3.y + wreg[4*k4+14]*h3.z + wreg[4*k4+15]*h3.w;
    }
    #pragma unroll
    for (int k4 = 0; k4 < 16; k4 += 4){
      float4 x0 = x4[k4], x1 = x4[k4+1], x2 = x4[k4+2], x3 = x4[k4+3];
      a0 += ureg[4*k4+0]*x0.x + ureg[4*k4+1]*x0.y + ureg[4*k4+2]*x0.z + ureg[4*k4+3]*x0.w;
      a1 += ureg[4*k4+4]*x1.x + ureg[4*k4+5]*x1.y + ureg[4*k4+6]*x1.z + ureg[4*k4+7]*x1.w;
      a2 += ureg[4*k4+8]*x2.x + ureg[4*k4+9]*x2.y + ureg[4*k4+10]*x2.z + ureg[4*k4+11]*x2.w;
      a3 += ureg[4*k4+12]*x3.x + ureg[4*k4+13]*x3.y + ureg[4*k4+14]*x3.z + ureg[4*k4+15]*x3.w;
    }
    gates[g] = (a0 + a1) + (a2 + a3);
    __syncthreads();
    if (g < 128){
      float i_ = sigm(gates[g]);
      float f_ = sigm(gates[128+g]);
      float g_ = tanhf(gates[256+g]);
      float o_ = sigm(gates[384+g]);
      creg = f_*creg + i_*g_;
      float h = o_ * tanhf(creg);
      hb[cur^1][g] = h;
      if (s >= 2) Hout[((s-2)*256 + b)*128 + g] = f2bf(h);
    } else if (g < 192 && s < 65){
      int l = g - 128;
      float v;
      if (s + 1 == 1) v = tgt[b*64 + l];
      else { int tok = inst[b*65 + (s - 1)]; v = embW[tok*64 + l]; }
      xb[cur^1][l] = v;
    }
    __syncthreads();
    cur ^= 1;
  }
}

// ---------------- K3: logits GEMM + log_softmax ----------------
// 512 blocks (64 t × 8 row-octets of 32 rows), 8 waves; each wave owns all 32
// rows (2 MFMA chains) and strides tiles by 8. Reg-double-buffered B loads,
// non-temporal output stores, raw barrier (no vmcnt drain) per chunk.
__global__ __launch_bounds__(512, 4) void k_out(
    const unsigned short* __restrict__ Hout, const unsigned short* __restrict__ WoutP,
    const float* __restrict__ boutP, float* __restrict__ out)
{
  int blk = blockIdx.x;
  int t = blk >> 3;
  int b0 = (blk & 7) * 32;
  int r0 = t*256 + b0;
  int tid = threadIdx.x;
  int w = tid >> 6;
  int l = tid & 63;
  int lm = l & 15;
  int lq = l >> 4;
  int kof = lq * 8;

  __shared__ float rs_l[8][32];
  __shared__ float lse_l[32];
  __shared__ float stage[2][32][132] __attribute__((aligned(16)));

  // A fragments: 32 rows (two 16-row groups), full K=128, in registers
  s16x8 af0[4], af1[4];
  {
    const s16x8* ap0 = (const s16x8*)(Hout + (size_t)(r0 + lm)*128 + kof);
    const s16x8* ap1 = (const s16x8*)(Hout + (size_t)(r0 + 16 + lm)*128 + kof);
    #pragma unroll
    for (int kk = 0; kk < 4; kk++){ af0[kk] = ap0[kk*4]; af1[kk] = ap1[kk*4]; }
  }

  s16x8 bA[4], bB[4];
#define LOADB(dst, tl) { \
    const s16x8* bp_ = (const s16x8*)(WoutP + (size_t)((tl)*16 + lm)*128 + kof); \
    dst[0] = bp_[0]; dst[1] = bp_[4]; dst[2] = bp_[8]; dst[3] = bp_[12]; }

  // ---- pass 1: row sums of exp(logit) ----
  float rs0[4] = {0,0,0,0}, rs1[4] = {0,0,0,0};
#define P1COMP(buf, tl) { \
    f32x4 a0_ = {0,0,0,0}, a1_ = {0,0,0,0}; \
    _Pragma("unroll") \
    for (int kk = 0; kk < 4; kk++){ \
      a0_ = __builtin_amdgcn_mfma_f32_16x16x32_bf16(af0[kk], buf[kk], a0_, 0, 0, 0); \
      a1_ = __builtin_amdgcn_mfma_f32_16x16x32_bf16(af1[kk], buf[kk], a1_, 0, 0, 0); } \
    float bo_ = boutP[(tl)*16 + lm]; \
    _Pragma("unroll") \
    for (int i = 0; i < 4; i++){ rs0[i] += __expf(a0_[i] + bo_); rs1[i] += __expf(a1_[i] + bo_); } }

  {
    int tl = w;
    LOADB(bA, tl);
    for (int it = 0; it < 39; it++){
      LOADB(bB, tl + 8);
      P1COMP(bA, tl);
      LOADB(bA, tl + 16);
      P1COMP(bB, tl + 8);
      tl += 16;
    }
    P1COMP(bA, tl);  // tile w + 624
  }

  #pragma unroll
  for (int i = 0; i < 4; i++){
    float s0 = rs0[i], s1 = rs1[i];
    s0 += __shfl_xor(s0, 1); s0 += __shfl_xor(s0, 2); s0 += __shfl_xor(s0, 4); s0 += __shfl_xor(s0, 8);
    s1 += __shfl_xor(s1, 1); s1 += __shfl_xor(s1, 2); s1 += __shfl_xor(s1, 4); s1 += __shfl_xor(s1, 8);
    rs0[i] = s0; rs1[i] = s1;
  }
  if (lm == 0){
    #pragma unroll
    for (int i = 0; i < 4; i++){
      rs_l[w][lq*4 + i] = rs0[i];
      rs_l[w][16 + lq*4 + i] = rs1[i];
    }
  }
  __syncthreads();
  if (tid < 32){
    float s = rs_l[0][tid] + rs_l[1][tid] + rs_l[2][tid] + rs_l[3][tid]
            + rs_l[4][tid] + rs_l[5][tid] + rs_l[6][tid] + rs_l[7][tid];
    lse_l[tid] = logf(s);
  }
  __syncthreads();
  float ml0[4], ml1[4];
  #pragma unroll
  for (int i = 0; i < 4; i++){ ml0[i] = lse_l[lq*4 + i]; ml1[i] = lse_l[16 + lq*4 + i]; }

  // ---- pass 2: recompute per 128-col chunk, LDS-stage, coalesced nt-stores ----
  int col = w*16 + lm;
#define P2COMP(buf, c) { \
    f32x4 a0_ = {0,0,0,0}, a1_ = {0,0,0,0}; \
    _Pragma("unroll") \
    for (int kk = 0; kk < 4; kk++){ \
      a0_ = __builtin_amdgcn_mfma_f32_16x16x32_bf16(af0[kk], buf[kk], a0_, 0, 0, 0); \
      a1_ = __builtin_amdgcn_mfma_f32_16x16x32_bf16(af1[kk], buf[kk], a1_, 0, 0, 0); } \
    float bo_ = boutP[((c)*8 + w)*16 + lm]; \
    float (*sb_)[132] = stage[(c) & 1]; \
    _Pragma("unroll") \
    for (int i = 0; i < 4; i++){ \
      sb_[lq*4 + i][col]      = a0_[i] + bo_ - ml0[i]; \
      sb_[16 + lq*4 + i][col] = a1_[i] + bo_ - ml1[i]; } }

#define BAR() { asm volatile("s_waitcnt lgkmcnt(0)" ::: "memory"); __builtin_amdgcn_s_barrier(); }

#define WPHASE(c) { \
    float (*sb_)[132] = stage[(c) & 1]; \
    int vbase_ = (c)*128; \
    if ((c) < 78){ \
      _Pragma("unroll") \
      for (int j = 0; j < 8; j++){ \
        int e_ = j*512 + tid; int row_ = e_ >> 7; int cc_ = e_ & 127; \
        size_t oidx_ = (size_t)((b0 + row_)*64 + t)*10001u + (unsigned)(vbase_ + cc_); \
        __builtin_nontemporal_store(sb_[row_][cc_], &out[oidx_]); } \
    } else { \
      _Pragma("unroll") \
      for (int j = 0; j < 8; j++){ \
        int e_ = j*512 + tid; int row_ = e_ >> 7; int cc_ = e_ & 127; \
        int v_ = vbase_ + cc_; \
        if (v_ < 10001){ \
          size_t oidx_ = (size_t)((b0 + row_)*64 + t)*10001u + (unsigned)v_; \
          __builtin_nontemporal_store(sb_[row_][cc_], &out[oidx_]); } } } }

  LOADB(bA, w);  // chunk 0's tile for this wave
  for (int cp = 0; cp < 39; cp++){
    int c = cp*2;
    LOADB(bB, (c + 1)*8 + w);
    P2COMP(bA, c);
    BAR();
    WPHASE(c);
    LOADB(bA, (c + 2)*8 + w);
    P2COMP(bB, c + 1);
    BAR();
    WPHASE(c + 1);
  }
  P2COMP(bA, 78);
  BAR();
  WPHASE(78);
}

// ---------------- host launcher ----------------
extern "C" void kernel_launch(void* const* d_in, const int* in_sizes, int n_in,
                              void* d_out, int out_size, void* d_ws, size_t ws_size,
                              hipStream_t stream)
{
  (void)in_sizes; (void)n_in; (void)out_size; (void)ws_size;
  const int*   inst    = (const int*)  d_in[0];
  const float* prevC   = (const float*)d_in[1];
  const float* finC    = (const float*)d_in[2];
  const float* tobj    = (const float*)d_in[3];
  const float* embW    = (const float*)d_in[4];
  const float* Wih     = (const float*)d_in[5];
  const float* Whh     = (const float*)d_in[6];
  const float* bih     = (const float*)d_in[7];
  const float* bhh     = (const float*)d_in[8];
  const float* Wout    = (const float*)d_in[9];
  const float* bout    = (const float*)d_in[10];
  const float* Wtgt    = (const float*)d_in[11];
  const float* btgt    = (const float*)d_in[12];
  const float* Wobj    = (const float*)d_in[13];
  const float* bobj    = (const float*)d_in[14];
  const float* ceWih   = (const float*)d_in[15];
  const float* ceWhh   = (const float*)d_in[16];
  const float* cebih   = (const float*)d_in[17];
  const float* cebhh   = (const float*)d_in[18];

  char* ws = (char*)d_ws;
  unsigned short* WoutP = (unsigned short*)(ws + 0);         // 10112*128*2 = 2,588,672
  float* boutP = (float*)(ws + 2588672);                     // 10112*4     = 40,448
  float* bsum  = (float*)(ws + 2629120);                     // 512*4       = 2,048
  float* tgt   = (float*)(ws + 2631168);                     // 256*64*4    = 65,536
  float* encP  = (float*)(ws + 2696704);                     // 256*64*4    = 65,536
  float* encF  = (float*)(ws + 2762240);                     // 256*64*4    = 65,536
  unsigned short* Hout = (unsigned short*)(ws + 2827776);    // 64*256*128*2 = 4,194,304
  float* out = (float*)d_out;

  k_prep  <<<5162, 256, 0, stream>>>(Wout, bout, bih, bhh, tobj, Wtgt, btgt,
                                     WoutP, boutP, bsum, tgt);
  k_canvas<<<512, 256, 0, stream>>>(prevC, finC, Wobj, bobj, ceWih, ceWhh,
                                    cebih, cebhh, encP, encF);
  k_rec   <<<256, 512, 0, stream>>>(Whh, Wih, bsum, inst, embW, tgt, encP, encF, Hout);
  k_out   <<<512, 512, 0, stream>>>(Hout, WoutP, boutP, out);
}